// Round 7
// baseline (2081.708 us; speedup 1.0000x reference)
//
#include <hip/hip_runtime.h>
#include <hip/hip_bf16.h>

#define BT 2
#define TT 1024
#define CC 2048
#define HH 32
#define MM (BT*TT)
#define TCH 64           // scan/prep chunk length
#define NCH (TT/TCH)     // 16 chunks
#define REC 384          // f32 per scan record: ew|r|kf|v|aa|bb (6 x 64)

static __device__ __forceinline__ float sigm(float x){ return 1.0f/(1.0f + expf(-x)); }

// ---------------- K1: rmsnorm(x_in, ln1) -> x_f f32, x[:, -1] -> seg1 f32 --------
__global__ __launch_bounds__(256) void rmsnorm1_kernel(
    const float* __restrict__ x_in,
    const float* __restrict__ ln1,
    float* __restrict__ x_f,
    float* __restrict__ x_last)
{
  const int m = blockIdx.x;
  const int tid = threadIdx.x;
  const int c = tid * 8;
  const float* xp = x_in + (size_t)m*CC + c;
  float v[8]; float ss = 0.f;
#pragma unroll
  for (int i=0;i<8;++i){ v[i] = xp[i]; ss += v[i]*v[i]; }
#pragma unroll
  for (int off=1; off<64; off<<=1) ss += __shfl_xor(ss, off);
  __shared__ float wsum[4];
  if ((tid&63)==0) wsum[tid>>6] = ss;
  __syncthreads();
  ss = wsum[0]+wsum[1]+wsum[2]+wsum[3];
  const float sc = rsqrtf(ss * (1.0f/CC) + 1e-6f);
#pragma unroll
  for (int i=0;i<8;++i) {
    const float y = ln1[c+i] * v[i] * sc;
    x_f[(size_t)m*CC + c + i] = y;
    if ((m % TT) == TT-1) x_last[(size_t)(m/TT)*CC + c + i] = y;
  }
}

// ---------------- textbook tiled SGEMM (f32): C[M,N] = A[M,K](lda) @ W[K,N] ------
__global__ __launch_bounds__(256) void sgemm(
    const float* __restrict__ A, int lda,
    const float* __restrict__ W,
    float* __restrict__ C, int N, int K)
{
  __shared__ float As[16][64];
  __shared__ float Ws[16][64];
  const int bm = blockIdx.x * 64;
  const int bn = blockIdx.y * 64;
  const int tid = threadIdx.x;
  const int tx = tid & 15, ty = tid >> 4;
  float acc[4][4] = {{0.f}};

  for (int k0 = 0; k0 < K; k0 += 16) {
    {
      const int idx = tid * 4;          // A: idx = m*16 + k
      const int m  = idx >> 4;
      const int kk = idx & 15;
      const float* ap = A + (size_t)(bm + m) * lda + k0 + kk;
      As[kk+0][m] = ap[0];
      As[kk+1][m] = ap[1];
      As[kk+2][m] = ap[2];
      As[kk+3][m] = ap[3];
      const int kw = idx >> 6;          // W: idx = k*64 + n
      const int n  = idx & 63;
      const float* wp = W + (size_t)(k0 + kw) * N + bn + n;
      Ws[kw][n+0] = wp[0];
      Ws[kw][n+1] = wp[1];
      Ws[kw][n+2] = wp[2];
      Ws[kw][n+3] = wp[3];
    }
    __syncthreads();
#pragma unroll
    for (int kk = 0; kk < 16; ++kk) {
      float a[4], b[4];
#pragma unroll
      for (int i=0;i<4;++i) a[i] = As[kk][ty*4+i];
#pragma unroll
      for (int j=0;j<4;++j) b[j] = Ws[kk][tx*4+j];
#pragma unroll
      for (int i=0;i<4;++i)
#pragma unroll
        for (int j=0;j<4;++j) acc[i][j] += a[i]*b[j];
    }
    __syncthreads();
  }
#pragma unroll
  for (int i=0;i<4;++i) {
    float* cp = C + (size_t)(bm + ty*4 + i) * N + bn + tx*4;
#pragma unroll
    for (int j=0;j<4;++j) cp[j] = acc[i][j];
  }
}

// ---------------- K4: activations on the 576-wide LoRA inputs (f32) --------------
__global__ void act576_kernel(const float* __restrict__ Y1, float* __restrict__ act)
{
  int i = blockIdx.x*256 + threadIdx.x;
  if (i >= MM*576) return;
  int col = i % 576;
  float v = Y1[i];
  if (col < 96) v = tanhf(v);                       // xw -> tanh
  else if (col >= 256 && col < 512) v = sigm(v);    // xg -> sigmoid
  act[i] = v;
}

// ---------------- K10: per-token prep -> f32 scan records + f32 bonus ------------
__global__ __launch_bounds__(256) void prep_kernel(
    const float* __restrict__ RKV,   // M x 3072 (r | k | v)
    const float* __restrict__ Wpre,  // M x 2048
    const float* __restrict__ Apre,  // M x 2048
    const float* __restrict__ Vsig,  // M x 512
    const float* __restrict__ Ksig,  // M x 512
    const float* __restrict__ v_first,
    const float* __restrict__ k_first,
    const float* __restrict__ cosp,
    const float* __restrict__ sinp,
    const float* __restrict__ ln_r,
    const float* __restrict__ ln_k,
    const float* __restrict__ r_k,
    const float* __restrict__ w0,
    const float* __restrict__ a0,
    const float* __restrict__ v0,
    const float* __restrict__ k0b,
    const float* __restrict__ R_bias,
    const float* __restrict__ K_bias,
    const float* __restrict__ V_bias,
    float* __restrict__ scan_chunk,  // [B*H*TCH] records of REC f32
    float* __restrict__ bonus,       // M x 2048 f32 (staged in seg5)
    int t0)
{
  const int b    = blockIdx.x / TCH;
  const int tloc = blockIdx.x % TCH;
  const int t    = t0 + tloc;
  const int m    = b*TT + t;
  const int tid = threadIdx.x;
  const int h  = tid >> 3;
  const int j  = tid & 7;
  const int hk = h >> 2;
  const int nb = j * 8;
  const int hn = h*64 + nb;    // into 2048-vectors
  const int kn = hk*64 + nb;   // into 512-vectors

  const size_t rbase = (size_t)m*3072 + h*64 + nb;
  const size_t kbase = (size_t)m*3072 + 2048 + kn;
  const size_t vbase = kbase + 512;

  float r[8], k[8], v[8];
  float ssr = 0.f, ssk = 0.f;
#pragma unroll
  for (int i=0;i<8;++i) {
    r[i] = RKV[rbase+i] + R_bias[hn+i];
    k[i] = RKV[kbase+i] + K_bias[kn+i];
    v[i] = RKV[vbase+i] + V_bias[kn+i];
    ssr += r[i]*r[i];
    ssk += k[i]*k[i];
  }
  ssr += __shfl_xor(ssr,1); ssr += __shfl_xor(ssr,2); ssr += __shfl_xor(ssr,4);
  ssk += __shfl_xor(ssk,1); ssk += __shfl_xor(ssk,2); ssk += __shfl_xor(ssk,4);
  const float scr = rsqrtf(ssr*(1.0f/64.0f) + 1e-6f);
  const float sck = rsqrtf(ssk*(1.0f/64.0f) + 1e-6f);
#pragma unroll
  for (int i=0;i<8;++i) {
    r[i] = ln_r[nb+i] * r[i] * scr;
    k[i] = ln_k[nb+i] * k[i] * sck;
  }
  // RoPE (rotate_half): partner lane is tid^4 (n +/- 32)
  const float sgn = (j < 4) ? -1.0f : 1.0f;
  float rr[8], kr[8];
#pragma unroll
  for (int i=0;i<8;++i) {
    const float cs = cosp[(size_t)m*64 + nb + i];
    const float sn = sinp[(size_t)m*64 + nb + i];
    const float pr = __shfl_xor(r[i], 4);
    const float pk = __shfl_xor(k[i], 4);
    rr[i] = r[i]*cs + sgn*pr*sn;
    kr[i] = k[i]*cs + sgn*pk*sn;
  }
  // v/k first-token mixing, a, w
  float av[8], ew[8], wv2[8];
  float ssn = 0.f;
#pragma unroll
  for (int i=0;i<8;++i) {
    const float vs = sigm(Vsig[(size_t)m*512 + kn + i] + v0[kn+i]);
    v[i]  = v[i]  + (v_first[(size_t)m*512 + kn + i] - v[i])  * vs;
    const float ks = sigm(Ksig[(size_t)m*512 + kn + i] + k0b[kn+i]);
    kr[i] = kr[i] + (k_first[(size_t)m*512 + kn + i] - kr[i]) * ks;
    ssn += kr[i]*kr[i];
    av[i] = sigm(Apre[(size_t)m*2048 + hn + i] + a0[hn+i]);
    float wraw = Wpre[(size_t)m*2048 + hn + i] + w0[hn+i];
    const float xs = -wraw;                              // stable softplus
    const float sp = fmaxf(xs, 0.f) + log1pf(expf(-fabsf(xs)));
    const float wv = -sp - 0.5f;                         // w = -softplus(-wraw)-0.5
    wv2[i] = wv;
    ew[i] = expf(-expf(wv));                             // exp(wlog)
  }
  ssn += __shfl_xor(ssn,1); ssn += __shfl_xor(ssn,2); ssn += __shfl_xor(ssn,4);
  const float inrm = 1.0f / (sqrtf(ssn) + 1e-12f);
  float kf[8], kkv[8];
  float bsum = 0.f;
#pragma unroll
  for (int i=0;i<8;++i) {
    kkv[i] = kr[i] * inrm;
    kf[i]  = kr[i] * (1.0f - wv2[i] + av[i]);
    bsum  += rr[i] * kf[i] * r_k[hn+i];
  }
  bsum += __shfl_xor(bsum,1); bsum += __shfl_xor(bsum,2); bsum += __shfl_xor(bsum,4);

  float* base = scan_chunk + ((size_t)(b*HH + h)*TCH + tloc)*REC;
#pragma unroll
  for (int i=0;i<8;++i) {
    base[      nb+i] = ew[i];
    base[ 64 + nb+i] = rr[i];
    base[128 + nb+i] = kf[i];
    base[192 + nb+i] = v[i];
    base[256 + nb+i] = -kkv[i];          // aa
    base[320 + nb+i] = kkv[i]*av[i];     // bb
    bonus[(size_t)m*2048 + hn + i] = bsum * v[i];
  }
}

// ---------------- K11: sequential RWKV7 scan over one chunk (all f32) ------------
__global__ __launch_bounds__(256) void scan_kernel(
    const float* __restrict__ scan_chunk,
    float* __restrict__ state,          // in-place f32 state [B*H,64,64]
    float* __restrict__ o_out,          // M x 2048 f32 (staged in seg0)
    int t0)
{
  const int blk = blockIdx.x;      // B*H*4
  const int q   = blk & 3;
  const int bh  = blk >> 2;        // b*H + h
  const int b   = bh >> 5, h = bh & 31;
  const int tid = threadIdx.x;
  const int vl  = q*16 + (tid >> 4);   // v row 0..63
  const int k4  = (tid & 15) * 4;      // k base
  const int klane = tid & 15;

  __shared__ float sbuf[REC];
  const float* base = scan_chunk + (size_t)bh * TCH * REC;

  float* sp = state + ((size_t)bh*64 + vl)*64 + k4;
  float S0=sp[0], S1=sp[1], S2=sp[2], S3=sp[3];

  for (int t = 0; t < TCH; ++t) {
    __syncthreads();                   // everyone done reading sbuf from t-1
    const float* rec = base + (size_t)t*REC;
    for (int u = tid; u < REC; u += 256) sbuf[u] = rec[u];
    __syncthreads();                   // record visible

    const float ew0 = sbuf[k4],     ew1 = sbuf[k4+1],     ew2 = sbuf[k4+2],     ew3 = sbuf[k4+3];
    const float r0  = sbuf[64+k4],  r1  = sbuf[64+k4+1],  r2  = sbuf[64+k4+2],  r3  = sbuf[64+k4+3];
    const float kf0 = sbuf[128+k4], kf1 = sbuf[128+k4+1], kf2 = sbuf[128+k4+2], kf3 = sbuf[128+k4+3];
    const float vfv = sbuf[192+vl];
    const float a0_ = sbuf[256+k4], a1_ = sbuf[256+k4+1], a2_ = sbuf[256+k4+2], a3_ = sbuf[256+k4+3];
    const float b0_ = sbuf[320+k4], b1_ = sbuf[320+k4+1], b2_ = sbuf[320+k4+2], b3_ = sbuf[320+k4+3];

    float sa = S0*a0_ + S1*a1_ + S2*a2_ + S3*a3_;
    sa += __shfl_xor(sa,1); sa += __shfl_xor(sa,2); sa += __shfl_xor(sa,4); sa += __shfl_xor(sa,8);

    S0 = S0*ew0 + sa*b0_ + vfv*kf0;
    S1 = S1*ew1 + sa*b1_ + vfv*kf1;
    S2 = S2*ew2 + sa*b2_ + vfv*kf2;
    S3 = S3*ew3 + sa*b3_ + vfv*kf3;

    float o = S0*r0 + S1*r1 + S2*r2 + S3*r3;
    o += __shfl_xor(o,1); o += __shfl_xor(o,2); o += __shfl_xor(o,4); o += __shfl_xor(o,8);
    if (klane == 0)
      o_out[(size_t)(b*TT + t0 + t)*CC + h*64 + vl] = o;
  }
  sp[0]=S0; sp[1]=S1; sp[2]=S2; sp[3]=S3;
}

// ---------------- K12: xxg = (o/8 + bonus) * g (all f32) -------------------------
__global__ void xxg_kernel(const float* __restrict__ o_in,
                           const float* __restrict__ bonus,
                           const float* __restrict__ G,
                           float* __restrict__ xxg)
{
  int i = blockIdx.x*256 + threadIdx.x;
  xxg[i] = (o_in[i]*0.125f + bonus[i]) * G[i];
}

// ---------------- K14: x_res = x_in + out; output = rmsnorm(x_res, ln2) ----------
__global__ __launch_bounds__(256) void final_kernel(
    const float* __restrict__ x_in,
    const float* __restrict__ OUTb,
    const float* __restrict__ ln2,
    float* __restrict__ seg0,
    float* __restrict__ seg5)
{
  const int m = blockIdx.x;
  const int tid = threadIdx.x;
  const int c = tid*8;
  const float* xp = x_in + (size_t)m*CC + c;
  const float* op = OUTb + (size_t)m*CC + c;
  float xr[8]; float ss = 0.f;
#pragma unroll
  for (int i=0;i<8;++i){ xr[i] = xp[i] + op[i]; ss += xr[i]*xr[i]; }
#pragma unroll
  for (int i=0;i<8;++i) seg5[(size_t)m*CC + c + i] = xr[i];
#pragma unroll
  for (int off=1; off<64; off<<=1) ss += __shfl_xor(ss, off);
  __shared__ float wsum[4];
  if ((tid&63)==0) wsum[tid>>6] = ss;
  __syncthreads();
  ss = wsum[0]+wsum[1]+wsum[2]+wsum[3];
  const float sc = rsqrtf(ss*(1.0f/CC) + 1e-6f);
#pragma unroll
  for (int i=0;i<8;++i) seg0[(size_t)m*CC + c + i] = ln2[c+i] * xr[i] * sc;
}

extern "C" void kernel_launch(void* const* d_in, const int* in_sizes, int n_in,
                              void* d_out, int out_size, void* d_ws, size_t ws_size,
                              hipStream_t stream)
{
  (void)in_sizes; (void)n_in; (void)out_size; (void)ws_size;
  const float* x_in   = (const float*)d_in[0];
  const float* v_first= (const float*)d_in[1];
  const float* k_first= (const float*)d_in[2];
  const float* state0 = (const float*)d_in[3];
  const float* cosp   = (const float*)d_in[4];
  const float* sinp   = (const float*)d_in[5];
  const float* ln1    = (const float*)d_in[6];
  const float* ln2    = (const float*)d_in[7];
  const float* ln_r   = (const float*)d_in[8];
  const float* ln_k   = (const float*)d_in[9];
  const float* wavgk1 = (const float*)d_in[10];
  const float* w0     = (const float*)d_in[11];
  const float* w2     = (const float*)d_in[12];
  const float* a0     = (const float*)d_in[13];
  const float* a2     = (const float*)d_in[14];
  const float* v0     = (const float*)d_in[15];
  const float* v2     = (const float*)d_in[16];
  const float* k0b    = (const float*)d_in[17];
  const float* k2     = (const float*)d_in[18];
  const float* g2     = (const float*)d_in[19];
  const float* r_k    = (const float*)d_in[20];
  const float* RKV_W  = (const float*)d_in[21];
  const float* O_W    = (const float*)d_in[22];
  const float* R_bias = (const float*)d_in[23];
  const float* K_bias = (const float*)d_in[24];
  const float* V_bias = (const float*)d_in[25];

  // ---- d_out is FLOAT32 (reference outputs are all jnp.float32) ----
  float* out  = (float*)d_out;
  float* seg0 = out;                 // output (B,T,C)        4,194,304 f32
  float* seg1 = out + 4194304;       // x[:, -1] (B,C)            4,096 f32
  float* seg2 = out + 4198400;       // state (B,H,N,N)         262,144 f32
  float* seg3 = out + 4460544;       // v_first (B,T,KVH,N)   1,048,576 f32
  float* seg4 = out + 5509120;       // k_first              1,048,576 f32
  float* seg5 = out + 6557696;       // x_res (B,T,C)         4,194,304 f32

  // ---- f32 workspace layout, peak ~117.4 MB ----
  char* ws = (char*)d_ws;
  const size_t OFF_STF  = 0;                                  // f32 state, 1,048,576 B
  const size_t OFF_SCIN = OFF_STF  + 1048576;                 // 6,291,456 B
  const size_t OFF_X    = OFF_SCIN + 6291456;                 // f32 M x 2048, 16,777,216 B
  const size_t OFF_Y1   = OFF_X    + (size_t)MM*CC*4;         // f32 M x 576, 4,718,592 B
  const size_t OFF_ACT  = OFF_Y1   + (size_t)MM*576*4;        // f32 M x 576
  const size_t OFF_RKV  = OFF_ACT  + (size_t)MM*576*4;        // f32 M x 3072, 25,165,824 B
  const size_t OFF_WPRE = OFF_RKV  + (size_t)MM*3072*4;       // f32 M x 2048
  const size_t OFF_APRE = OFF_WPRE + (size_t)MM*CC*4;
  const size_t OFF_G    = OFF_APRE + (size_t)MM*CC*4;
  const size_t OFF_VSIG = OFF_G    + (size_t)MM*CC*4;         // f32 M x 512
  const size_t OFF_KSIG = OFF_VSIG + (size_t)MM*512*4;        // end = 117,440,512 B
  // overlays (strictly after their regions die):
  const size_t OFF_XXG  = OFF_X;                              // x dead after wavgk1/RKV gemms
  const size_t OFF_OUT  = OFF_RKV;                            // RKV dead after last prep

  float* stf   = (float*)(ws + OFF_STF);
  float* scin  = (float*)(ws + OFF_SCIN);
  float* x_f   = (float*)(ws + OFF_X);
  float* Y1    = (float*)(ws + OFF_Y1);
  float* act   = (float*)(ws + OFF_ACT);
  float* RKV   = (float*)(ws + OFF_RKV);
  float* Wpre  = (float*)(ws + OFF_WPRE);
  float* Apre  = (float*)(ws + OFF_APRE);
  float* Gbuf  = (float*)(ws + OFF_G);
  float* Vsig  = (float*)(ws + OFF_VSIG);
  float* Ksig  = (float*)(ws + OFF_KSIG);
  float* xxg   = (float*)(ws + OFF_XXG);
  float* OUTb  = (float*)(ws + OFF_OUT);

  // o staged in seg0, bonus staged in seg5 (both fully rewritten by final_kernel)
  float* o_st = seg0;
  float* b_st = seg5;

  rmsnorm1_kernel<<<MM, 256, 0, stream>>>(x_in, ln1, x_f, seg1);
  sgemm<<<dim3(MM/64,  576/64), 256, 0, stream>>>(x_f, CC, wavgk1, Y1, 576, CC);
  sgemm<<<dim3(MM/64, 3072/64), 256, 0, stream>>>(x_f, CC, RKV_W, RKV, 3072, CC);
  act576_kernel<<<(MM*576+255)/256, 256, 0, stream>>>(Y1, act);
  sgemm<<<dim3(MM/64, 2048/64), 256, 0, stream>>>(act+0,   576, w2, Wpre, 2048, 96);
  sgemm<<<dim3(MM/64, 2048/64), 256, 0, stream>>>(act+96,  576, a2, Apre, 2048, 96);
  sgemm<<<dim3(MM/64,  512/64), 256, 0, stream>>>(act+192, 576, v2, Vsig,  512, 64);
  sgemm<<<dim3(MM/64,  512/64), 256, 0, stream>>>(act+512, 576, k2, Ksig,  512, 64);
  sgemm<<<dim3(MM/64, 2048/64), 256, 0, stream>>>(act+256, 576, g2, Gbuf, 2048, 256);

  hipMemcpyAsync(stf, state0, (size_t)1048576, hipMemcpyDeviceToDevice, stream);
  for (int c = 0; c < NCH; ++c) {
    const int t0 = c*TCH;
    prep_kernel<<<BT*TCH, 256, 0, stream>>>(RKV, Wpre, Apre, Vsig, Ksig, v_first, k_first,
                                            cosp, sinp, ln_r, ln_k, r_k, w0, a0, v0, k0b,
                                            R_bias, K_bias, V_bias, scin, b_st, t0);
    scan_kernel<<<BT*HH*4, 256, 0, stream>>>(scin, stf, o_st, t0);
  }
  // state output: exact f32 copy
  hipMemcpyAsync(seg2, stf, (size_t)1048576, hipMemcpyDeviceToDevice, stream);

  xxg_kernel<<<(MM*CC)/256, 256, 0, stream>>>(o_st, b_st, Gbuf, xxg);
  sgemm<<<dim3(MM/64, 2048/64), 256, 0, stream>>>(xxg, CC, O_W, OUTb, 2048, CC);
  final_kernel<<<MM, 256, 0, stream>>>(x_in, OUTb, ln2, seg0, seg5);

  // v_first / k_first echo: exact f32 copies
  hipMemcpyAsync(seg3, v_first, (size_t)1048576*4, hipMemcpyDeviceToDevice, stream);
  hipMemcpyAsync(seg4, k_first, (size_t)1048576*4, hipMemcpyDeviceToDevice, stream);
}

// Round 8
// 952.254 us; speedup vs baseline: 2.1861x; 2.1861x over previous
//
#include <hip/hip_runtime.h>
#include <hip/hip_bf16.h>

#define BT 2
#define TT 1024
#define CC 2048
#define HH 32
#define MM (BT*TT)
#define TCH 512          // scan/prep chunk length
#define NCH (TT/TCH)     // 2 chunks
#define RECB 896         // bytes per scan record: ew f32[64] | r,kf,v,kk,a bf16[64]

typedef __attribute__((ext_vector_type(8))) short short8;
typedef __attribute__((ext_vector_type(4))) float floatx4;

static __device__ __forceinline__ float bf2f(__hip_bfloat16 x){ return __bfloat162float(x); }
static __device__ __forceinline__ __hip_bfloat16 f2bf(float x){ return __float2bfloat16(x); }
static __device__ __forceinline__ float sigm(float x){ return 1.0f/(1.0f + expf(-x)); }
static __device__ __forceinline__ float u2f(unsigned short u){
  union { unsigned int i; float f; } x; x.i = ((unsigned int)u) << 16; return x.f;
}

// ---------------- K0: transpose + convert weights: Wt[n][k] = bf16(W[k][n]) ------
__global__ __launch_bounds__(256) void tcvt_kernel(
    const float* __restrict__ W, __hip_bfloat16* __restrict__ Wt,
    int K, int N, int Npad)
{
  __shared__ float tile[32][33];
  const int bn = blockIdx.x*32, bk = blockIdx.y*32;
  const int tx = threadIdx.x & 31, ty0 = threadIdx.x >> 5;   // 8 rows/pass
#pragma unroll
  for (int i=0;i<4;++i){
    const int kk = bk + ty0 + i*8;
    float val = 0.f;
    if (kk < K && bn + tx < N) val = W[(size_t)kk*N + bn + tx];
    tile[ty0 + i*8][tx] = val;
  }
  __syncthreads();
#pragma unroll
  for (int i=0;i<4;++i){
    const int nn = bn + ty0 + i*8;
    const int kk = bk + tx;
    if (nn < Npad && kk < K) Wt[(size_t)nn*K + kk] = f2bf(tile[tx][ty0 + i*8]);
  }
}

// ---------------- K1: rmsnorm(x_in, ln1) -> x_bf bf16; x[:, -1] -> seg1 f32 ------
__global__ __launch_bounds__(256) void rmsnorm1_kernel(
    const float* __restrict__ x_in,
    const float* __restrict__ ln1,
    __hip_bfloat16* __restrict__ x_bf,
    float* __restrict__ x_last)
{
  const int m = blockIdx.x;
  const int tid = threadIdx.x;
  const int c = tid * 8;
  const float* xp = x_in + (size_t)m*CC + c;
  float v[8]; float ss = 0.f;
#pragma unroll
  for (int i=0;i<8;++i){ v[i] = xp[i]; ss += v[i]*v[i]; }
#pragma unroll
  for (int off=1; off<64; off<<=1) ss += __shfl_xor(ss, off);
  __shared__ float wsum[4];
  if ((tid&63)==0) wsum[tid>>6] = ss;
  __syncthreads();
  ss = wsum[0]+wsum[1]+wsum[2]+wsum[3];
  const float sc = rsqrtf(ss * (1.0f/CC) + 1e-6f);
#pragma unroll
  for (int i=0;i<8;++i) {
    const float y = ln1[c+i] * v[i] * sc;
    x_bf[(size_t)m*CC + c + i] = f2bf(y);
    if ((m % TT) == TT-1) x_last[(size_t)(m/TT)*CC + c + i] = y;
  }
}

// ------- MFMA bf16 GEMM: C[M,N] = A_bf16[M,K](lda) @ Wt_bf16[Npad,K]^T -----------
// 128x128 tile, 4 waves in 2x2, 16 MFMA(16x16x32) per k-step, single LDS buffer.
template<bool F32OUT>
__global__ __launch_bounds__(256) void mgemm(
    const __hip_bfloat16* __restrict__ A, int lda,
    const __hip_bfloat16* __restrict__ Bt,
    void* __restrict__ C, int N, int K)
{
  __shared__ __align__(16) short As[128*32];
  __shared__ __align__(16) short Bs[128*32];
  const int tid = threadIdx.x;
  const int bm = blockIdx.x * 128;
  const int bn = blockIdx.y * 128;
  const int wid = tid >> 6;
  const int lane = tid & 63;
  const int m16 = lane & 15, quad = lane >> 4;
  const int wm = wid & 1, wn = wid >> 1;
  const int lrow = tid >> 2;          // 0..63
  const int lcol = (tid & 3) * 8;     // bf16 elems: 0,8,16,24

  floatx4 acc[4][4];
#pragma unroll
  for (int i=0;i<4;++i)
#pragma unroll
    for (int j=0;j<4;++j) acc[i][j] = (floatx4){0.f,0.f,0.f,0.f};

  for (int k0 = 0; k0 < K; k0 += 32) {
    __syncthreads();
    uint4 a0v = *(const uint4*)(const void*)(A  + (size_t)(bm + lrow)      * lda + k0 + lcol);
    uint4 a1v = *(const uint4*)(const void*)(A  + (size_t)(bm + 64 + lrow) * lda + k0 + lcol);
    uint4 b0v = *(const uint4*)(const void*)(Bt + (size_t)(bn + lrow)      * K   + k0 + lcol);
    uint4 b1v = *(const uint4*)(const void*)(Bt + (size_t)(bn + 64 + lrow) * K   + k0 + lcol);
    *(uint4*)(void*)(As + lrow*32 + lcol)        = a0v;
    *(uint4*)(void*)(As + (64 + lrow)*32 + lcol) = a1v;
    *(uint4*)(void*)(Bs + lrow*32 + lcol)        = b0v;
    *(uint4*)(void*)(Bs + (64 + lrow)*32 + lcol) = b1v;
    __syncthreads();

    short8 af[4], bfg[4];
#pragma unroll
    for (int mi=0; mi<4; ++mi)
      af[mi] = *(const short8*)(const void*)(As + (wm*64 + mi*16 + m16)*32 + quad*8);
#pragma unroll
    for (int ni=0; ni<4; ++ni)
      bfg[ni] = *(const short8*)(const void*)(Bs + (wn*64 + ni*16 + m16)*32 + quad*8);
#pragma unroll
    for (int mi=0; mi<4; ++mi)
#pragma unroll
      for (int ni=0; ni<4; ++ni)
        acc[mi][ni] = __builtin_amdgcn_mfma_f32_16x16x32_bf16(af[mi], bfg[ni], acc[mi][ni], 0,0,0);
  }

#pragma unroll
  for (int mi=0; mi<4; ++mi) {
    const int row = bm + wm*64 + mi*16 + quad*4;
#pragma unroll
    for (int ni=0; ni<4; ++ni) {
      const int col = bn + wn*64 + ni*16 + m16;
      if (col < N) {
        if (F32OUT) {
          float* cp = (float*)C;
#pragma unroll
          for (int r=0;r<4;++r) cp[(size_t)(row+r)*N + col] = acc[mi][ni][r];
        } else {
          __hip_bfloat16* cp = (__hip_bfloat16*)C;
#pragma unroll
          for (int r=0;r<4;++r) cp[(size_t)(row+r)*N + col] = f2bf(acc[mi][ni][r]);
        }
      }
    }
  }
}

// ---------------- K4: activations on the 576-wide LoRA inputs, in-place bf16 -----
__global__ void act576_kernel(__hip_bfloat16* __restrict__ Y1)
{
  int i = blockIdx.x*256 + threadIdx.x;
  if (i >= MM*576) return;
  int col = i % 576;
  float v = bf2f(Y1[i]);
  if (col < 96) v = tanhf(v);                       // xw -> tanh
  else if (col >= 256 && col < 512) v = sigm(v);    // xg -> sigmoid
  Y1[i] = f2bf(v);
}

// ---------------- K10: per-token prep -> packed records + f32 bonus --------------
__global__ __launch_bounds__(256) void prep_kernel(
    const __hip_bfloat16* __restrict__ RKV,   // M x 3072 (r | k | v) bf16
    const __hip_bfloat16* __restrict__ Wpre,  // M x 2048 bf16
    const __hip_bfloat16* __restrict__ Apre,  // M x 2048 bf16
    const __hip_bfloat16* __restrict__ Vsig,  // M x 512 bf16
    const __hip_bfloat16* __restrict__ Ksig,  // M x 512 bf16
    const float* __restrict__ v_first,
    const float* __restrict__ k_first,
    const float* __restrict__ cosp,
    const float* __restrict__ sinp,
    const float* __restrict__ ln_r,
    const float* __restrict__ ln_k,
    const float* __restrict__ r_k,
    const float* __restrict__ w0,
    const float* __restrict__ a0,
    const float* __restrict__ v0,
    const float* __restrict__ k0b,
    const float* __restrict__ R_bias,
    const float* __restrict__ K_bias,
    const float* __restrict__ V_bias,
    char* __restrict__ rec,          // [B*H*TCH] records of RECB bytes
    float* __restrict__ bonus,       // M x 2048 f32 (seg5 staging)
    int t0)
{
  const int b    = blockIdx.x / TCH;
  const int tloc = blockIdx.x % TCH;
  const int t    = t0 + tloc;
  const int m    = b*TT + t;
  const int tid = threadIdx.x;
  const int h  = tid >> 3;
  const int j  = tid & 7;
  const int hk = h >> 2;
  const int nb = j * 8;
  const int hn = h*64 + nb;
  const int kn = hk*64 + nb;

  const size_t rbase = (size_t)m*3072 + h*64 + nb;
  const size_t kbase = (size_t)m*3072 + 2048 + kn;
  const size_t vbase = kbase + 512;

  float r[8], k[8], v[8];
  float ssr = 0.f, ssk = 0.f;
#pragma unroll
  for (int i=0;i<8;++i) {
    r[i] = bf2f(RKV[rbase+i]) + R_bias[hn+i];
    k[i] = bf2f(RKV[kbase+i]) + K_bias[kn+i];
    v[i] = bf2f(RKV[vbase+i]) + V_bias[kn+i];
    ssr += r[i]*r[i];
    ssk += k[i]*k[i];
  }
  ssr += __shfl_xor(ssr,1); ssr += __shfl_xor(ssr,2); ssr += __shfl_xor(ssr,4);
  ssk += __shfl_xor(ssk,1); ssk += __shfl_xor(ssk,2); ssk += __shfl_xor(ssk,4);
  const float scr = rsqrtf(ssr*(1.0f/64.0f) + 1e-6f);
  const float sck = rsqrtf(ssk*(1.0f/64.0f) + 1e-6f);
#pragma unroll
  for (int i=0;i<8;++i) {
    r[i] = ln_r[nb+i] * r[i] * scr;
    k[i] = ln_k[nb+i] * k[i] * sck;
  }
  const float sgn = (j < 4) ? -1.0f : 1.0f;
  float rr[8], kr[8];
#pragma unroll
  for (int i=0;i<8;++i) {
    const float cs = cosp[(size_t)m*64 + nb + i];
    const float sn = sinp[(size_t)m*64 + nb + i];
    const float pr = __shfl_xor(r[i], 4);
    const float pk = __shfl_xor(k[i], 4);
    rr[i] = r[i]*cs + sgn*pr*sn;
    kr[i] = k[i]*cs + sgn*pk*sn;
  }
  float av[8], ew[8], wv2[8];
  float ssn = 0.f;
#pragma unroll
  for (int i=0;i<8;++i) {
    const float vs = sigm(bf2f(Vsig[(size_t)m*512 + kn + i]) + v0[kn+i]);
    v[i]  = v[i]  + (v_first[(size_t)m*512 + kn + i] - v[i])  * vs;
    const float ks = sigm(bf2f(Ksig[(size_t)m*512 + kn + i]) + k0b[kn+i]);
    kr[i] = kr[i] + (k_first[(size_t)m*512 + kn + i] - kr[i]) * ks;
    ssn += kr[i]*kr[i];
    av[i] = sigm(bf2f(Apre[(size_t)m*2048 + hn + i]) + a0[hn+i]);
    float wraw = bf2f(Wpre[(size_t)m*2048 + hn + i]) + w0[hn+i];
    const float xs = -wraw;                              // stable softplus
    const float sp = fmaxf(xs, 0.f) + log1pf(expf(-fabsf(xs)));
    const float wv = -sp - 0.5f;
    wv2[i] = wv;
    ew[i] = expf(-expf(wv));
  }
  ssn += __shfl_xor(ssn,1); ssn += __shfl_xor(ssn,2); ssn += __shfl_xor(ssn,4);
  const float inrm = 1.0f / (sqrtf(ssn) + 1e-12f);
  float kf[8], kkv[8];
  float bsum = 0.f;
#pragma unroll
  for (int i=0;i<8;++i) {
    kkv[i] = kr[i] * inrm;
    kf[i]  = kr[i] * (1.0f - wv2[i] + av[i]);
    bsum  += rr[i] * kf[i] * r_k[hn+i];
  }
  bsum += __shfl_xor(bsum,1); bsum += __shfl_xor(bsum,2); bsum += __shfl_xor(bsum,4);

  char* base = rec + ((size_t)(b*HH + h)*TCH + tloc)*RECB;
  float* ewp = (float*)base;                               // 64 f32
  __hip_bfloat16* rp  = (__hip_bfloat16*)(base + 256);
  __hip_bfloat16* kfp = (__hip_bfloat16*)(base + 384);
  __hip_bfloat16* vp  = (__hip_bfloat16*)(base + 512);
  __hip_bfloat16* kkp = (__hip_bfloat16*)(base + 640);
  __hip_bfloat16* ap  = (__hip_bfloat16*)(base + 768);
#pragma unroll
  for (int i=0;i<8;++i) {
    ewp[nb+i] = ew[i];
    rp [nb+i] = f2bf(rr[i]);
    kfp[nb+i] = f2bf(kf[i]);
    vp [nb+i] = f2bf(v[i]);
    kkp[nb+i] = f2bf(kkv[i]);
    ap [nb+i] = f2bf(av[i]);
    bonus[(size_t)m*2048 + hn + i] = bsum * v[i];
  }
}

// ---------------- K11: RWKV7 scan, no LDS/no barriers, register prefetch ---------
// grid: B*H*8 blocks, 128 threads (8 v-rows x 16 k-lanes), 4 f32 state/thread.
__global__ __launch_bounds__(128) void scan_kernel(
    const char* __restrict__ rec,
    float* __restrict__ state,          // f32 [B*H,64,64], carried across chunks
    float* __restrict__ o_out,          // M x 2048 f32 (seg0 staging)
    int t0)
{
  const int blk = blockIdx.x;
  const int q   = blk & 7;
  const int bh  = blk >> 3;
  const int b   = bh >> 5, h = bh & 31;
  const int tid = threadIdx.x;
  const int vl  = q*8 + (tid >> 4);    // v row 0..63
  const int k4  = (tid & 15) * 4;      // k base
  const int klane = tid & 15;

  const char* base = rec + (size_t)bh * TCH * RECB;
  float* sp = state + ((size_t)bh*64 + vl)*64 + k4;
  float S0=sp[0], S1=sp[1], S2=sp[2], S3=sp[3];

  const char* p = base;
  float4  ew_c = *(const float4*)(const void*)(p + k4*4);
  ushort4 r_c  = *(const ushort4*)(const void*)(p + 256 + k4*2);
  ushort4 kf_c = *(const ushort4*)(const void*)(p + 384 + k4*2);
  unsigned short v_c = *(const unsigned short*)(const void*)(p + 512 + vl*2);
  ushort4 kk_c = *(const ushort4*)(const void*)(p + 640 + k4*2);
  ushort4 a_c  = *(const ushort4*)(const void*)(p + 768 + k4*2);

  for (int t = 0; t < TCH; ++t) {
    const char* pn = base + (size_t)(t+1 < TCH ? t+1 : t)*RECB;
    float4  ew_n = *(const float4*)(const void*)(pn + k4*4);
    ushort4 r_n  = *(const ushort4*)(const void*)(pn + 256 + k4*2);
    ushort4 kf_n = *(const ushort4*)(const void*)(pn + 384 + k4*2);
    unsigned short v_n = *(const unsigned short*)(const void*)(pn + 512 + vl*2);
    ushort4 kk_n = *(const ushort4*)(const void*)(pn + 640 + k4*2);
    ushort4 a_n  = *(const ushort4*)(const void*)(pn + 768 + k4*2);

    const float kk0 = u2f(kk_c.x), kk1 = u2f(kk_c.y), kk2 = u2f(kk_c.z), kk3 = u2f(kk_c.w);
    float sa = -(S0*kk0 + S1*kk1 + S2*kk2 + S3*kk3);
    sa += __shfl_xor(sa,1); sa += __shfl_xor(sa,2); sa += __shfl_xor(sa,4); sa += __shfl_xor(sa,8);

    const float vf = u2f(v_c);
    const float b0 = kk0*u2f(a_c.x), b1 = kk1*u2f(a_c.y), b2 = kk2*u2f(a_c.z), b3 = kk3*u2f(a_c.w);
    S0 = S0*ew_c.x + sa*b0 + vf*u2f(kf_c.x);
    S1 = S1*ew_c.y + sa*b1 + vf*u2f(kf_c.y);
    S2 = S2*ew_c.z + sa*b2 + vf*u2f(kf_c.z);
    S3 = S3*ew_c.w + sa*b3 + vf*u2f(kf_c.w);

    float o = S0*u2f(r_c.x) + S1*u2f(r_c.y) + S2*u2f(r_c.z) + S3*u2f(r_c.w);
    o += __shfl_xor(o,1); o += __shfl_xor(o,2); o += __shfl_xor(o,4); o += __shfl_xor(o,8);
    if (klane == 0)
      o_out[(size_t)(b*TT + t0 + t)*CC + h*64 + vl] = o;

    ew_c = ew_n; r_c = r_n; kf_c = kf_n; v_c = v_n; kk_c = kk_n; a_c = a_n;
  }
  sp[0]=S0; sp[1]=S1; sp[2]=S2; sp[3]=S3;
}

// ---------------- K12: xxg = (o/8 + bonus) * g -> bf16 ---------------------------
__global__ void xxg_kernel(const float* __restrict__ o_in,
                           const float* __restrict__ bonus,
                           const __hip_bfloat16* __restrict__ G,
                           __hip_bfloat16* __restrict__ xxg)
{
  int i = blockIdx.x*256 + threadIdx.x;
  xxg[i] = f2bf((o_in[i]*0.125f + bonus[i]) * bf2f(G[i]));
}

// ---------------- K14: x_res = x_in + out; output = rmsnorm(x_res, ln2) ----------
__global__ __launch_bounds__(256) void final_kernel(
    const float* __restrict__ x_in,
    const float* __restrict__ OUTb,
    const float* __restrict__ ln2,
    float* __restrict__ seg0,
    float* __restrict__ seg5)
{
  const int m = blockIdx.x;
  const int tid = threadIdx.x;
  const int c = tid*8;
  const float* xp = x_in + (size_t)m*CC + c;
  const float* op = OUTb + (size_t)m*CC + c;
  float xr[8]; float ss = 0.f;
#pragma unroll
  for (int i=0;i<8;++i){ xr[i] = xp[i] + op[i]; ss += xr[i]*xr[i]; }
#pragma unroll
  for (int i=0;i<8;++i) seg5[(size_t)m*CC + c + i] = xr[i];
#pragma unroll
  for (int off=1; off<64; off<<=1) ss += __shfl_xor(ss, off);
  __shared__ float wsum[4];
  if ((tid&63)==0) wsum[tid>>6] = ss;
  __syncthreads();
  ss = wsum[0]+wsum[1]+wsum[2]+wsum[3];
  const float sc = rsqrtf(ss*(1.0f/CC) + 1e-6f);
#pragma unroll
  for (int i=0;i<8;++i) seg0[(size_t)m*CC + c + i] = ln2[c+i] * xr[i] * sc;
}

extern "C" void kernel_launch(void* const* d_in, const int* in_sizes, int n_in,
                              void* d_out, int out_size, void* d_ws, size_t ws_size,
                              hipStream_t stream)
{
  (void)in_sizes; (void)n_in; (void)out_size; (void)ws_size;
  const float* x_in   = (const float*)d_in[0];
  const float* v_first= (const float*)d_in[1];
  const float* k_first= (const float*)d_in[2];
  const float* state0 = (const float*)d_in[3];
  const float* cosp   = (const float*)d_in[4];
  const float* sinp   = (const float*)d_in[5];
  const float* ln1    = (const float*)d_in[6];
  const float* ln2    = (const float*)d_in[7];
  const float* ln_r   = (const float*)d_in[8];
  const float* ln_k   = (const float*)d_in[9];
  const float* wavgk1 = (const float*)d_in[10];
  const float* w0     = (const float*)d_in[11];
  const float* w2     = (const float*)d_in[12];
  const float* a0     = (const float*)d_in[13];
  const float* a2     = (const float*)d_in[14];
  const float* v0     = (const float*)d_in[15];
  const float* v2     = (const float*)d_in[16];
  const float* k0b    = (const float*)d_in[17];
  const float* k2     = (const float*)d_in[18];
  const float* g2     = (const float*)d_in[19];
  const float* r_k    = (const float*)d_in[20];
  const float* RKV_W  = (const float*)d_in[21];
  const float* O_W    = (const float*)d_in[22];
  const float* R_bias = (const float*)d_in[23];
  const float* K_bias = (const float*)d_in[24];
  const float* V_bias = (const float*)d_in[25];

  // ---- d_out is FLOAT32 ----
  float* out  = (float*)d_out;
  float* seg0 = out;                 // output (B,T,C)
  float* seg1 = out + 4194304;       // x[:, -1] (B,C)
  float* seg2 = out + 4198400;       // state
  float* seg3 = out + 4460544;       // v_first
  float* seg4 = out + 5509120;       // k_first
  float* seg5 = out + 6557696;       // x_res (B,T,C)

  // ---- workspace layout, peak 91,488,256 B (~87.3 MiB) ----
  char* ws = (char*)d_ws;
  const size_t OFF_STF   = 0;                     // f32 state, 1,048,576
  const size_t OFF_OWT   = 1048576;               // O_W^T bf16 2048x2048, 8,388,608
  const size_t OFF_G     = 9437184;               // bf16 M x 2048, 8,388,608
  const size_t OFF_VSIG  = 17825792;              // bf16 M x 512, 2,097,152
  const size_t OFF_KSIG  = 19922944;              // bf16 M x 512
  const size_t OFF_WPRE  = 22020096;              // bf16 M x 2048, 8,388,608
  const size_t OFF_APRE  = 30408704;              // bf16 M x 2048
  const size_t OFF_RKV   = 38797312;              // bf16 M x 3072, 12,582,912
  const size_t OFF_XBF   = 51380224;              // bf16 M x 2048 (dead after x GEMMs)
  const size_t OFF_Y1    = 59768832;              // bf16 M x 576, 2,359,296 (act in-place)
  const size_t OFF_WT    = 62128128;              // transposed weights (dead after GEMMs)
  const size_t OFF_WAVT  = OFF_WT;                //  640x2048 bf16, 2,621,440
  const size_t OFF_RKVT  = OFF_WAVT + 2621440;    // 3072x2048 bf16, 12,582,912
  const size_t OFF_W2T   = OFF_RKVT + 12582912;   // 2048x96 bf16, 393,216
  const size_t OFF_A2T   = OFF_W2T  + 393216;
  const size_t OFF_V2T   = OFF_A2T  + 393216;     // 512x64 bf16, 65,536
  const size_t OFF_K2T   = OFF_V2T  + 65536;
  const size_t OFF_G2T   = OFF_K2T  + 65536;      // 2048x256 bf16, 1,048,576
  // overlays:
  const size_t OFF_REC   = OFF_WT;                // records 64*512*896 = 29,360,128 (over WT, dead)
  const size_t OFF_XXG   = OFF_XBF;               // bf16 M x 2048 over x_bf (dead)
  const size_t OFF_OUT   = OFF_WPRE;              // f32 M x 2048 over Wpre+Apre (dead)

  float*          stf   = (float*)(ws + OFF_STF);
  __hip_bfloat16* owt   = (__hip_bfloat16*)(ws + OFF_OWT);
  __hip_bfloat16* Gbuf  = (__hip_bfloat16*)(ws + OFF_G);
  __hip_bfloat16* Vsig  = (__hip_bfloat16*)(ws + OFF_VSIG);
  __hip_bfloat16* Ksig  = (__hip_bfloat16*)(ws + OFF_KSIG);
  __hip_bfloat16* Wpre  = (__hip_bfloat16*)(ws + OFF_WPRE);
  __hip_bfloat16* Apre  = (__hip_bfloat16*)(ws + OFF_APRE);
  __hip_bfloat16* RKV   = (__hip_bfloat16*)(ws + OFF_RKV);
  __hip_bfloat16* x_bf  = (__hip_bfloat16*)(ws + OFF_XBF);
  __hip_bfloat16* Y1    = (__hip_bfloat16*)(ws + OFF_Y1);
  __hip_bfloat16* wavt  = (__hip_bfloat16*)(ws + OFF_WAVT);
  __hip_bfloat16* rkvt  = (__hip_bfloat16*)(ws + OFF_RKVT);
  __hip_bfloat16* w2t   = (__hip_bfloat16*)(ws + OFF_W2T);
  __hip_bfloat16* a2t   = (__hip_bfloat16*)(ws + OFF_A2T);
  __hip_bfloat16* v2t   = (__hip_bfloat16*)(ws + OFF_V2T);
  __hip_bfloat16* k2t   = (__hip_bfloat16*)(ws + OFF_K2T);
  __hip_bfloat16* g2t   = (__hip_bfloat16*)(ws + OFF_G2T);
  char*           rec   = ws + OFF_REC;
  __hip_bfloat16* xxg   = (__hip_bfloat16*)(ws + OFF_XXG);
  float*          OUTb  = (float*)(ws + OFF_OUT);

  float* o_st = seg0;   // o staged in seg0 (rewritten by final)
  float* b_st = seg5;   // bonus staged in seg5 (rewritten by final)

  // weight transposes (f32 -> bf16, [K,N] -> [Npad,K])
  tcvt_kernel<<<dim3(20, 64), 256, 0, stream>>>(wavgk1, wavt, 2048, 576, 640);
  tcvt_kernel<<<dim3(96, 64), 256, 0, stream>>>(RKV_W,  rkvt, 2048, 3072, 3072);
  tcvt_kernel<<<dim3(64, 64), 256, 0, stream>>>(O_W,    owt,  2048, 2048, 2048);
  tcvt_kernel<<<dim3(64,  3), 256, 0, stream>>>(w2,     w2t,    96, 2048, 2048);
  tcvt_kernel<<<dim3(64,  3), 256, 0, stream>>>(a2,     a2t,    96, 2048, 2048);
  tcvt_kernel<<<dim3(16,  2), 256, 0, stream>>>(v2,     v2t,    64,  512,  512);
  tcvt_kernel<<<dim3(16,  2), 256, 0, stream>>>(k2,     k2t,    64,  512,  512);
  tcvt_kernel<<<dim3(64,  8), 256, 0, stream>>>(g2,     g2t,   256, 2048, 2048);

  rmsnorm1_kernel<<<MM, 256, 0, stream>>>(x_in, ln1, x_bf, seg1);
  mgemm<false><<<dim3(16,  5), 256, 0, stream>>>(x_bf, CC, wavt, Y1,   576, 2048);
  mgemm<false><<<dim3(16, 24), 256, 0, stream>>>(x_bf, CC, rkvt, RKV, 3072, 2048);
  act576_kernel<<<(MM*576+255)/256, 256, 0, stream>>>(Y1);
  mgemm<false><<<dim3(16, 16), 256, 0, stream>>>(Y1+0,   576, w2t, Wpre, 2048, 96);
  mgemm<false><<<dim3(16, 16), 256, 0, stream>>>(Y1+96,  576, a2t, Apre, 2048, 96);
  mgemm<false><<<dim3(16,  4), 256, 0, stream>>>(Y1+192, 576, v2t, Vsig,  512, 64);
  mgemm<false><<<dim3(16,  4), 256, 0, stream>>>(Y1+512, 576, k2t, Ksig,  512, 64);
  mgemm<false><<<dim3(16, 16), 256, 0, stream>>>(Y1+256, 576, g2t, Gbuf, 2048, 256);

  hipMemcpyAsync(stf, state0, (size_t)1048576, hipMemcpyDeviceToDevice, stream);
  for (int c = 0; c < NCH; ++c) {
    const int t0 = c*TCH;
    prep_kernel<<<BT*TCH, 256, 0, stream>>>(RKV, Wpre, Apre, Vsig, Ksig, v_first, k_first,
                                            cosp, sinp, ln_r, ln_k, r_k, w0, a0, v0, k0b,
                                            R_bias, K_bias, V_bias, rec, b_st, t0);
    scan_kernel<<<BT*HH*8, 128, 0, stream>>>(rec, stf, o_st, t0);
  }
  hipMemcpyAsync(seg2, stf, (size_t)1048576, hipMemcpyDeviceToDevice, stream);

  xxg_kernel<<<(MM*CC)/256, 256, 0, stream>>>(o_st, b_st, Gbuf, xxg);
  mgemm<true><<<dim3(16, 16), 256, 0, stream>>>(xxg, CC, owt, OUTb, 2048, 2048);
  final_kernel<<<MM, 256, 0, stream>>>(x_in, OUTb, ln2, seg0, seg5);

  hipMemcpyAsync(seg3, v_first, (size_t)1048576*4, hipMemcpyDeviceToDevice, stream);
  hipMemcpyAsync(seg4, k_first, (size_t)1048576*4, hipMemcpyDeviceToDevice, stream);
}

// Round 9
// 863.768 us; speedup vs baseline: 2.4100x; 1.1024x over previous
//
#include <hip/hip_runtime.h>
#include <hip/hip_bf16.h>

#define BT 2
#define TT 1024
#define CC 2048
#define HH 32
#define MM (BT*TT)
#define TCH 512          // scan/prep chunk length
#define NCH (TT/TCH)     // 2 chunks
#define RECB 896         // bytes per scan record: ew f32[64] | r,kf,v,kk,a bf16[64]

typedef __attribute__((ext_vector_type(8))) short short8;
typedef __attribute__((ext_vector_type(4))) float floatx4;

static __device__ __forceinline__ float bf2f(__hip_bfloat16 x){ return __bfloat162float(x); }
static __device__ __forceinline__ __hip_bfloat16 f2bf(float x){ return __float2bfloat16(x); }
static __device__ __forceinline__ float sigm(float x){ return 1.0f/(1.0f + expf(-x)); }
static __device__ __forceinline__ float u2f(unsigned short u){
  union { unsigned int i; float f; } x; x.i = ((unsigned int)u) << 16; return x.f;
}
static __device__ __forceinline__ float ulo(unsigned int u){ return u2f((unsigned short)(u & 0xffffu)); }
static __device__ __forceinline__ float uhi(unsigned int u){ return u2f((unsigned short)(u >> 16)); }

// ---------------- K0: transpose + convert weights: Wt[n][k] = bf16(W[k][n]) ------
__global__ __launch_bounds__(256) void tcvt_kernel(
    const float* __restrict__ W, __hip_bfloat16* __restrict__ Wt,
    int K, int N, int Npad)
{
  __shared__ float tile[32][33];
  const int bn = blockIdx.x*32, bk = blockIdx.y*32;
  const int tx = threadIdx.x & 31, ty0 = threadIdx.x >> 5;   // 8 rows/pass
#pragma unroll
  for (int i=0;i<4;++i){
    const int kk = bk + ty0 + i*8;
    float val = 0.f;
    if (kk < K && bn + tx < N) val = W[(size_t)kk*N + bn + tx];
    tile[ty0 + i*8][tx] = val;
  }
  __syncthreads();
#pragma unroll
  for (int i=0;i<4;++i){
    const int nn = bn + ty0 + i*8;
    const int kk = bk + tx;
    if (nn < Npad && kk < K) Wt[(size_t)nn*K + kk] = f2bf(tile[tx][ty0 + i*8]);
  }
}

// ---------------- K1: rmsnorm(x_in, ln1) -> x_bf bf16; x[:, -1] -> seg1 f32 ------
__global__ __launch_bounds__(256) void rmsnorm1_kernel(
    const float* __restrict__ x_in,
    const float* __restrict__ ln1,
    __hip_bfloat16* __restrict__ x_bf,
    float* __restrict__ x_last)
{
  const int m = blockIdx.x;
  const int tid = threadIdx.x;
  const int c = tid * 8;
  const float* xp = x_in + (size_t)m*CC + c;
  float v[8]; float ss = 0.f;
#pragma unroll
  for (int i=0;i<8;++i){ v[i] = xp[i]; ss += v[i]*v[i]; }
#pragma unroll
  for (int off=1; off<64; off<<=1) ss += __shfl_xor(ss, off);
  __shared__ float wsum[4];
  if ((tid&63)==0) wsum[tid>>6] = ss;
  __syncthreads();
  ss = wsum[0]+wsum[1]+wsum[2]+wsum[3];
  const float sc = rsqrtf(ss * (1.0f/CC) + 1e-6f);
#pragma unroll
  for (int i=0;i<8;++i) {
    const float y = ln1[c+i] * v[i] * sc;
    x_bf[(size_t)m*CC + c + i] = f2bf(y);
    if ((m % TT) == TT-1) x_last[(size_t)(m/TT)*CC + c + i] = y;
  }
}

// ------- MFMA bf16 GEMM: C[M,N] = A_bf16[M,K](lda) @ Wt_bf16[Npad,K]^T -----------
template<bool F32OUT>
__global__ __launch_bounds__(256) void mgemm(
    const __hip_bfloat16* __restrict__ A, int lda,
    const __hip_bfloat16* __restrict__ Bt,
    void* __restrict__ C, int N, int K)
{
  __shared__ __align__(16) short As[128*32];
  __shared__ __align__(16) short Bs[128*32];
  const int tid = threadIdx.x;
  const int bm = blockIdx.x * 128;
  const int bn = blockIdx.y * 128;
  const int wid = tid >> 6;
  const int lane = tid & 63;
  const int m16 = lane & 15, quad = lane >> 4;
  const int wm = wid & 1, wn = wid >> 1;
  const int lrow = tid >> 2;          // 0..63
  const int lcol = (tid & 3) * 8;     // bf16 elems: 0,8,16,24

  floatx4 acc[4][4];
#pragma unroll
  for (int i=0;i<4;++i)
#pragma unroll
    for (int j=0;j<4;++j) acc[i][j] = (floatx4){0.f,0.f,0.f,0.f};

  for (int k0 = 0; k0 < K; k0 += 32) {
    __syncthreads();
    uint4 a0v = *(const uint4*)(const void*)(A  + (size_t)(bm + lrow)      * lda + k0 + lcol);
    uint4 a1v = *(const uint4*)(const void*)(A  + (size_t)(bm + 64 + lrow) * lda + k0 + lcol);
    uint4 b0v = *(const uint4*)(const void*)(Bt + (size_t)(bn + lrow)      * K   + k0 + lcol);
    uint4 b1v = *(const uint4*)(const void*)(Bt + (size_t)(bn + 64 + lrow) * K   + k0 + lcol);
    *(uint4*)(void*)(As + lrow*32 + lcol)        = a0v;
    *(uint4*)(void*)(As + (64 + lrow)*32 + lcol) = a1v;
    *(uint4*)(void*)(Bs + lrow*32 + lcol)        = b0v;
    *(uint4*)(void*)(Bs + (64 + lrow)*32 + lcol) = b1v;
    __syncthreads();

    short8 af[4], bfg[4];
#pragma unroll
    for (int mi=0; mi<4; ++mi)
      af[mi] = *(const short8*)(const void*)(As + (wm*64 + mi*16 + m16)*32 + quad*8);
#pragma unroll
    for (int ni=0; ni<4; ++ni)
      bfg[ni] = *(const short8*)(const void*)(Bs + (wn*64 + ni*16 + m16)*32 + quad*8);
#pragma unroll
    for (int mi=0; mi<4; ++mi)
#pragma unroll
      for (int ni=0; ni<4; ++ni)
        acc[mi][ni] = __builtin_amdgcn_mfma_f32_16x16x32_bf16(af[mi], bfg[ni], acc[mi][ni], 0,0,0);
  }

#pragma unroll
  for (int mi=0; mi<4; ++mi) {
    const int row = bm + wm*64 + mi*16 + quad*4;
#pragma unroll
    for (int ni=0; ni<4; ++ni) {
      const int col = bn + wn*64 + ni*16 + m16;
      if (col < N) {
        if (F32OUT) {
          float* cp = (float*)C;
#pragma unroll
          for (int r=0;r<4;++r) cp[(size_t)(row+r)*N + col] = acc[mi][ni][r];
        } else {
          __hip_bfloat16* cp = (__hip_bfloat16*)C;
#pragma unroll
          for (int r=0;r<4;++r) cp[(size_t)(row+r)*N + col] = f2bf(acc[mi][ni][r]);
        }
      }
    }
  }
}

// ---------------- K4: activations on the 576-wide LoRA inputs, in-place bf16 -----
__global__ void act576_kernel(__hip_bfloat16* __restrict__ Y1)
{
  int i = blockIdx.x*256 + threadIdx.x;
  if (i >= MM*576) return;
  int col = i % 576;
  float v = bf2f(Y1[i]);
  if (col < 96) v = tanhf(v);                       // xw -> tanh
  else if (col >= 256 && col < 512) v = sigm(v);    // xg -> sigmoid
  Y1[i] = f2bf(v);
}

// ---------------- K10: per-token prep -> packed records + f32 bonus --------------
__global__ __launch_bounds__(256) void prep_kernel(
    const __hip_bfloat16* __restrict__ RKV,   // M x 3072 (r | k | v) bf16
    const __hip_bfloat16* __restrict__ Wpre,  // M x 2048 bf16
    const __hip_bfloat16* __restrict__ Apre,  // M x 2048 bf16
    const __hip_bfloat16* __restrict__ Vsig,  // M x 512 bf16
    const __hip_bfloat16* __restrict__ Ksig,  // M x 512 bf16
    const float* __restrict__ v_first,
    const float* __restrict__ k_first,
    const float* __restrict__ cosp,
    const float* __restrict__ sinp,
    const float* __restrict__ ln_r,
    const float* __restrict__ ln_k,
    const float* __restrict__ r_k,
    const float* __restrict__ w0,
    const float* __restrict__ a0,
    const float* __restrict__ v0,
    const float* __restrict__ k0b,
    const float* __restrict__ R_bias,
    const float* __restrict__ K_bias,
    const float* __restrict__ V_bias,
    char* __restrict__ rec,          // [B*H*TCH] records of RECB bytes
    float* __restrict__ bonus,       // M x 2048 f32 (seg5 staging)
    int t0)
{
  const int b    = blockIdx.x / TCH;
  const int tloc = blockIdx.x % TCH;
  const int t    = t0 + tloc;
  const int m    = b*TT + t;
  const int tid = threadIdx.x;
  const int h  = tid >> 3;
  const int j  = tid & 7;
  const int hk = h >> 2;
  const int nb = j * 8;
  const int hn = h*64 + nb;
  const int kn = hk*64 + nb;

  const size_t rbase = (size_t)m*3072 + h*64 + nb;
  const size_t kbase = (size_t)m*3072 + 2048 + kn;
  const size_t vbase = kbase + 512;

  float r[8], k[8], v[8];
  float ssr = 0.f, ssk = 0.f;
#pragma unroll
  for (int i=0;i<8;++i) {
    r[i] = bf2f(RKV[rbase+i]) + R_bias[hn+i];
    k[i] = bf2f(RKV[kbase+i]) + K_bias[kn+i];
    v[i] = bf2f(RKV[vbase+i]) + V_bias[kn+i];
    ssr += r[i]*r[i];
    ssk += k[i]*k[i];
  }
  ssr += __shfl_xor(ssr,1); ssr += __shfl_xor(ssr,2); ssr += __shfl_xor(ssr,4);
  ssk += __shfl_xor(ssk,1); ssk += __shfl_xor(ssk,2); ssk += __shfl_xor(ssk,4);
  const float scr = rsqrtf(ssr*(1.0f/64.0f) + 1e-6f);
  const float sck = rsqrtf(ssk*(1.0f/64.0f) + 1e-6f);
#pragma unroll
  for (int i=0;i<8;++i) {
    r[i] = ln_r[nb+i] * r[i] * scr;
    k[i] = ln_k[nb+i] * k[i] * sck;
  }
  const float sgn = (j < 4) ? -1.0f : 1.0f;
  float rr[8], kr[8];
#pragma unroll
  for (int i=0;i<8;++i) {
    const float cs = cosp[(size_t)m*64 + nb + i];
    const float sn = sinp[(size_t)m*64 + nb + i];
    const float pr = __shfl_xor(r[i], 4);
    const float pk = __shfl_xor(k[i], 4);
    rr[i] = r[i]*cs + sgn*pr*sn;
    kr[i] = k[i]*cs + sgn*pk*sn;
  }
  float av[8], ew[8], wv2[8];
  float ssn = 0.f;
#pragma unroll
  for (int i=0;i<8;++i) {
    const float vs = sigm(bf2f(Vsig[(size_t)m*512 + kn + i]) + v0[kn+i]);
    v[i]  = v[i]  + (v_first[(size_t)m*512 + kn + i] - v[i])  * vs;
    const float ks = sigm(bf2f(Ksig[(size_t)m*512 + kn + i]) + k0b[kn+i]);
    kr[i] = kr[i] + (k_first[(size_t)m*512 + kn + i] - kr[i]) * ks;
    ssn += kr[i]*kr[i];
    av[i] = sigm(bf2f(Apre[(size_t)m*2048 + hn + i]) + a0[hn+i]);
    float wraw = bf2f(Wpre[(size_t)m*2048 + hn + i]) + w0[hn+i];
    const float xs = -wraw;                              // stable softplus
    const float sp = fmaxf(xs, 0.f) + log1pf(expf(-fabsf(xs)));
    const float wv = -sp - 0.5f;
    wv2[i] = wv;
    ew[i] = expf(-expf(wv));
  }
  ssn += __shfl_xor(ssn,1); ssn += __shfl_xor(ssn,2); ssn += __shfl_xor(ssn,4);
  const float inrm = 1.0f / (sqrtf(ssn) + 1e-12f);
  float kf[8], kkv[8];
  float bsum = 0.f;
#pragma unroll
  for (int i=0;i<8;++i) {
    kkv[i] = kr[i] * inrm;
    kf[i]  = kr[i] * (1.0f - wv2[i] + av[i]);
    bsum  += rr[i] * kf[i] * r_k[hn+i];
  }
  bsum += __shfl_xor(bsum,1); bsum += __shfl_xor(bsum,2); bsum += __shfl_xor(bsum,4);

  char* base = rec + ((size_t)(b*HH + h)*TCH + tloc)*RECB;
  float* ewp = (float*)base;                               // 64 f32
  __hip_bfloat16* rp  = (__hip_bfloat16*)(base + 256);
  __hip_bfloat16* kfp = (__hip_bfloat16*)(base + 384);
  __hip_bfloat16* vp  = (__hip_bfloat16*)(base + 512);
  __hip_bfloat16* kkp = (__hip_bfloat16*)(base + 640);
  __hip_bfloat16* ap  = (__hip_bfloat16*)(base + 768);
#pragma unroll
  for (int i=0;i<8;++i) {
    ewp[nb+i] = ew[i];
    rp [nb+i] = f2bf(rr[i]);
    kfp[nb+i] = f2bf(kf[i]);
    vp [nb+i] = f2bf(v[i]);
    kkp[nb+i] = f2bf(kkv[i]);
    ap [nb+i] = f2bf(av[i]);
    bonus[(size_t)m*2048 + hn + i] = bsum * v[i];
  }
}

// ---------------- K11: RWKV7 scan v2 ---------------------------------------------
// 256 thr = 8 v-rows x 32 k-lanes (2 k/lane); grid B*H*8; bh in LOW bits so all
// 8 q-blocks of one bh land on the same XCD (blk%8 == bh%8) -> records hit L2.
// Depth-2 register prefetch; o-reduction of step t deferred to step t+1 so the
// two dependent shuffle chains (sa, o) interleave.
__global__ __launch_bounds__(256) void scan_kernel(
    const char* __restrict__ rec,
    float* __restrict__ state,          // f32 [B*H,64,64], carried across chunks
    float* __restrict__ o_out,          // M x 2048 f32 (seg0 staging)
    int t0)
{
  const int blk = blockIdx.x;
  const int bh  = blk & 63;            // XCD-local grouping
  const int q   = blk >> 6;
  const int b   = bh >> 5, h = bh & 31;
  const int tid = threadIdx.x;
  const int vl  = q*8 + (tid >> 5);    // v row 0..63
  const int kl  = tid & 31;            // k lane
  const int k2  = kl*2;

  const char* base = rec + (size_t)bh * TCH * RECB;
  float* sp = state + ((size_t)bh*64 + vl)*64 + k2;
  float S0=sp[0], S1=sp[1];

  float2 ewA, ewB; unsigned int rA,rB, kfA,kfB, kkA,kkB, aA,aB;
  unsigned short vA, vB;
  {
    const char* p0 = base;
    ewA = *(const float2*)(const void*)(p0 + k2*4);
    rA  = *(const unsigned int*)(const void*)(p0 + 256 + kl*4);
    kfA = *(const unsigned int*)(const void*)(p0 + 384 + kl*4);
    vA  = *(const unsigned short*)(const void*)(p0 + 512 + vl*2);
    kkA = *(const unsigned int*)(const void*)(p0 + 640 + kl*4);
    aA  = *(const unsigned int*)(const void*)(p0 + 768 + kl*4);
    const char* p1 = base + (TCH > 1 ? RECB : 0);
    ewB = *(const float2*)(const void*)(p1 + k2*4);
    rB  = *(const unsigned int*)(const void*)(p1 + 256 + kl*4);
    kfB = *(const unsigned int*)(const void*)(p1 + 384 + kl*4);
    vB  = *(const unsigned short*)(const void*)(p1 + 512 + vl*2);
    kkB = *(const unsigned int*)(const void*)(p1 + 640 + kl*4);
    aB  = *(const unsigned int*)(const void*)(p1 + 768 + kl*4);
  }

  float opart = 0.f;
  for (int t = 0; t < TCH; ++t) {
    const int tn = (t+2 < TCH) ? t+2 : TCH-1;
    const char* pn = base + (size_t)tn*RECB;
    float2 ewC = *(const float2*)(const void*)(pn + k2*4);
    unsigned int rC  = *(const unsigned int*)(const void*)(pn + 256 + kl*4);
    unsigned int kfC = *(const unsigned int*)(const void*)(pn + 384 + kl*4);
    unsigned short vC = *(const unsigned short*)(const void*)(pn + 512 + vl*2);
    unsigned int kkC = *(const unsigned int*)(const void*)(pn + 640 + kl*4);
    unsigned int aC  = *(const unsigned int*)(const void*)(pn + 768 + kl*4);

    // deferred o-reduction of step t-1 (independent of the sa chain below)
    float op = opart;
    op += __shfl_xor(op,1); op += __shfl_xor(op,2); op += __shfl_xor(op,4);
    op += __shfl_xor(op,8); op += __shfl_xor(op,16);

    // sa chain
    const float kk0 = ulo(kkA), kk1 = uhi(kkA);
    float sa = S0*kk0 + S1*kk1;
    sa += __shfl_xor(sa,1); sa += __shfl_xor(sa,2); sa += __shfl_xor(sa,4);
    sa += __shfl_xor(sa,8); sa += __shfl_xor(sa,16);
    sa = -sa;                                        // aa = -kk

    if (kl == 0 && t > 0)
      o_out[(size_t)(b*TT + t0 + t - 1)*CC + h*64 + vl] = op;

    const float vf = u2f(vA);
    S0 = S0*ewA.x + sa*(kk0*ulo(aA)) + vf*ulo(kfA);
    S1 = S1*ewA.y + sa*(kk1*uhi(aA)) + vf*uhi(kfA);
    opart = S0*ulo(rA) + S1*uhi(rA);

    ewA=ewB; rA=rB; kfA=kfB; vA=vB; kkA=kkB; aA=aB;
    ewB=ewC; rB=rC; kfB=kfC; vB=vC; kkB=kkC; aB=aC;
  }
  opart += __shfl_xor(opart,1); opart += __shfl_xor(opart,2); opart += __shfl_xor(opart,4);
  opart += __shfl_xor(opart,8); opart += __shfl_xor(opart,16);
  if (kl == 0)
    o_out[(size_t)(b*TT + t0 + TCH - 1)*CC + h*64 + vl] = opart;

  sp[0]=S0; sp[1]=S1;
}

// ---------------- K12: xxg = (o/8 + bonus) * g -> bf16 ---------------------------
__global__ void xxg_kernel(const float* __restrict__ o_in,
                           const float* __restrict__ bonus,
                           const __hip_bfloat16* __restrict__ G,
                           __hip_bfloat16* __restrict__ xxg)
{
  int i = blockIdx.x*256 + threadIdx.x;
  xxg[i] = f2bf((o_in[i]*0.125f + bonus[i]) * bf2f(G[i]));
}

// ---------------- K14: x_res = x_in + out; output = rmsnorm(x_res, ln2) ----------
__global__ __launch_bounds__(256) void final_kernel(
    const float* __restrict__ x_in,
    const float* __restrict__ OUTb,
    const float* __restrict__ ln2,
    float* __restrict__ seg0,
    float* __restrict__ seg5)
{
  const int m = blockIdx.x;
  const int tid = threadIdx.x;
  const int c = tid*8;
  const float* xp = x_in + (size_t)m*CC + c;
  const float* op = OUTb + (size_t)m*CC + c;
  float xr[8]; float ss = 0.f;
#pragma unroll
  for (int i=0;i<8;++i){ xr[i] = xp[i] + op[i]; ss += xr[i]*xr[i]; }
#pragma unroll
  for (int i=0;i<8;++i) seg5[(size_t)m*CC + c + i] = xr[i];
#pragma unroll
  for (int off=1; off<64; off<<=1) ss += __shfl_xor(ss, off);
  __shared__ float wsum[4];
  if ((tid&63)==0) wsum[tid>>6] = ss;
  __syncthreads();
  ss = wsum[0]+wsum[1]+wsum[2]+wsum[3];
  const float sc = rsqrtf(ss*(1.0f/CC) + 1e-6f);
#pragma unroll
  for (int i=0;i<8;++i) seg0[(size_t)m*CC + c + i] = ln2[c+i] * xr[i] * sc;
}

extern "C" void kernel_launch(void* const* d_in, const int* in_sizes, int n_in,
                              void* d_out, int out_size, void* d_ws, size_t ws_size,
                              hipStream_t stream)
{
  (void)in_sizes; (void)n_in; (void)out_size; (void)ws_size;
  const float* x_in   = (const float*)d_in[0];
  const float* v_first= (const float*)d_in[1];
  const float* k_first= (const float*)d_in[2];
  const float* state0 = (const float*)d_in[3];
  const float* cosp   = (const float*)d_in[4];
  const float* sinp   = (const float*)d_in[5];
  const float* ln1    = (const float*)d_in[6];
  const float* ln2    = (const float*)d_in[7];
  const float* ln_r   = (const float*)d_in[8];
  const float* ln_k   = (const float*)d_in[9];
  const float* wavgk1 = (const float*)d_in[10];
  const float* w0     = (const float*)d_in[11];
  const float* w2     = (const float*)d_in[12];
  const float* a0     = (const float*)d_in[13];
  const float* a2     = (const float*)d_in[14];
  const float* v0     = (const float*)d_in[15];
  const float* v2     = (const float*)d_in[16];
  const float* k0b    = (const float*)d_in[17];
  const float* k2     = (const float*)d_in[18];
  const float* g2     = (const float*)d_in[19];
  const float* r_k    = (const float*)d_in[20];
  const float* RKV_W  = (const float*)d_in[21];
  const float* O_W    = (const float*)d_in[22];
  const float* R_bias = (const float*)d_in[23];
  const float* K_bias = (const float*)d_in[24];
  const float* V_bias = (const float*)d_in[25];

  // ---- d_out is FLOAT32 ----
  float* out  = (float*)d_out;
  float* seg0 = out;                 // output (B,T,C)
  float* seg1 = out + 4194304;       // x[:, -1] (B,C)
  float* seg2 = out + 4198400;       // state
  float* seg3 = out + 4460544;       // v_first
  float* seg4 = out + 5509120;       // k_first
  float* seg5 = out + 6557696;       // x_res (B,T,C)

  // ---- workspace layout, peak 91,488,256 B (~87.3 MiB) ----
  char* ws = (char*)d_ws;
  const size_t OFF_STF   = 0;                     // f32 state, 1,048,576
  const size_t OFF_OWT   = 1048576;               // O_W^T bf16 2048x2048, 8,388,608
  const size_t OFF_G     = 9437184;               // bf16 M x 2048, 8,388,608
  const size_t OFF_VSIG  = 17825792;              // bf16 M x 512, 2,097,152
  const size_t OFF_KSIG  = 19922944;              // bf16 M x 512
  const size_t OFF_WPRE  = 22020096;              // bf16 M x 2048, 8,388,608
  const size_t OFF_APRE  = 30408704;              // bf16 M x 2048
  const size_t OFF_RKV   = 38797312;              // bf16 M x 3072, 12,582,912
  const size_t OFF_XBF   = 51380224;              // bf16 M x 2048 (dead after x GEMMs)
  const size_t OFF_Y1    = 59768832;              // bf16 M x 576, 2,359,296 (act in-place)
  const size_t OFF_WT    = 62128128;              // transposed weights (dead after GEMMs)
  const size_t OFF_WAVT  = OFF_WT;                //  640x2048 bf16, 2,621,440
  const size_t OFF_RKVT  = OFF_WAVT + 2621440;    // 3072x2048 bf16, 12,582,912
  const size_t OFF_W2T   = OFF_RKVT + 12582912;   // 2048x96 bf16, 393,216
  const size_t OFF_A2T   = OFF_W2T  + 393216;
  const size_t OFF_V2T   = OFF_A2T  + 393216;     // 512x64 bf16, 65,536
  const size_t OFF_K2T   = OFF_V2T  + 65536;
  const size_t OFF_G2T   = OFF_K2T  + 65536;      // 2048x256 bf16, 1,048,576
  // overlays:
  const size_t OFF_REC   = OFF_WT;                // records 64*512*896 = 29,360,128 (over WT, dead)
  const size_t OFF_XXG   = OFF_XBF;               // bf16 M x 2048 over x_bf (dead)
  const size_t OFF_OUT   = OFF_WPRE;              // f32 M x 2048 over Wpre+Apre (dead)

  float*          stf   = (float*)(ws + OFF_STF);
  __hip_bfloat16* owt   = (__hip_bfloat16*)(ws + OFF_OWT);
  __hip_bfloat16* Gbuf  = (__hip_bfloat16*)(ws + OFF_G);
  __hip_bfloat16* Vsig  = (__hip_bfloat16*)(ws + OFF_VSIG);
  __hip_bfloat16* Ksig  = (__hip_bfloat16*)(ws + OFF_KSIG);
  __hip_bfloat16* Wpre  = (__hip_bfloat16*)(ws + OFF_WPRE);
  __hip_bfloat16* Apre  = (__hip_bfloat16*)(ws + OFF_APRE);
  __hip_bfloat16* RKV   = (__hip_bfloat16*)(ws + OFF_RKV);
  __hip_bfloat16* x_bf  = (__hip_bfloat16*)(ws + OFF_XBF);
  __hip_bfloat16* Y1    = (__hip_bfloat16*)(ws + OFF_Y1);
  __hip_bfloat16* wavt  = (__hip_bfloat16*)(ws + OFF_WAVT);
  __hip_bfloat16* rkvt  = (__hip_bfloat16*)(ws + OFF_RKVT);
  __hip_bfloat16* w2t   = (__hip_bfloat16*)(ws + OFF_W2T);
  __hip_bfloat16* a2t   = (__hip_bfloat16*)(ws + OFF_A2T);
  __hip_bfloat16* v2t   = (__hip_bfloat16*)(ws + OFF_V2T);
  __hip_bfloat16* k2t   = (__hip_bfloat16*)(ws + OFF_K2T);
  __hip_bfloat16* g2t   = (__hip_bfloat16*)(ws + OFF_G2T);
  char*           rec   = ws + OFF_REC;
  __hip_bfloat16* xxg   = (__hip_bfloat16*)(ws + OFF_XXG);
  float*          OUTb  = (float*)(ws + OFF_OUT);

  float* o_st = seg0;   // o staged in seg0 (rewritten by final)
  float* b_st = seg5;   // bonus staged in seg5 (rewritten by final)

  // weight transposes (f32 -> bf16, [K,N] -> [Npad,K])
  tcvt_kernel<<<dim3(20, 64), 256, 0, stream>>>(wavgk1, wavt, 2048, 576, 640);
  tcvt_kernel<<<dim3(96, 64), 256, 0, stream>>>(RKV_W,  rkvt, 2048, 3072, 3072);
  tcvt_kernel<<<dim3(64, 64), 256, 0, stream>>>(O_W,    owt,  2048, 2048, 2048);
  tcvt_kernel<<<dim3(64,  3), 256, 0, stream>>>(w2,     w2t,    96, 2048, 2048);
  tcvt_kernel<<<dim3(64,  3), 256, 0, stream>>>(a2,     a2t,    96, 2048, 2048);
  tcvt_kernel<<<dim3(16,  2), 256, 0, stream>>>(v2,     v2t,    64,  512,  512);
  tcvt_kernel<<<dim3(16,  2), 256, 0, stream>>>(k2,     k2t,    64,  512,  512);
  tcvt_kernel<<<dim3(64,  8), 256, 0, stream>>>(g2,     g2t,   256, 2048, 2048);

  rmsnorm1_kernel<<<MM, 256, 0, stream>>>(x_in, ln1, x_bf, seg1);
  mgemm<false><<<dim3(16,  5), 256, 0, stream>>>(x_bf, CC, wavt, Y1,   576, 2048);
  mgemm<false><<<dim3(16, 24), 256, 0, stream>>>(x_bf, CC, rkvt, RKV, 3072, 2048);
  act576_kernel<<<(MM*576+255)/256, 256, 0, stream>>>(Y1);
  mgemm<false><<<dim3(16, 16), 256, 0, stream>>>(Y1+0,   576, w2t, Wpre, 2048, 96);
  mgemm<false><<<dim3(16, 16), 256, 0, stream>>>(Y1+96,  576, a2t, Apre, 2048, 96);
  mgemm<false><<<dim3(16,  4), 256, 0, stream>>>(Y1+192, 576, v2t, Vsig,  512, 64);
  mgemm<false><<<dim3(16,  4), 256, 0, stream>>>(Y1+512, 576, k2t, Ksig,  512, 64);
  mgemm<false><<<dim3(16, 16), 256, 0, stream>>>(Y1+256, 576, g2t, Gbuf, 2048, 256);

  hipMemcpyAsync(stf, state0, (size_t)1048576, hipMemcpyDeviceToDevice, stream);
  for (int c = 0; c < NCH; ++c) {
    const int t0 = c*TCH;
    prep_kernel<<<BT*TCH, 256, 0, stream>>>(RKV, Wpre, Apre, Vsig, Ksig, v_first, k_first,
                                            cosp, sinp, ln_r, ln_k, r_k, w0, a0, v0, k0b,
                                            R_bias, K_bias, V_bias, rec, b_st, t0);
    scan_kernel<<<BT*HH*8, 256, 0, stream>>>(rec, stf, o_st, t0);
  }
  hipMemcpyAsync(seg2, stf, (size_t)1048576, hipMemcpyDeviceToDevice, stream);

  xxg_kernel<<<(MM*CC)/256, 256, 0, stream>>>(o_st, b_st, Gbuf, xxg);
  mgemm<true><<<dim3(16, 16), 256, 0, stream>>>(xxg, CC, owt, OUTb, 2048, 2048);
  final_kernel<<<MM, 256, 0, stream>>>(x_in, OUTb, ln2, seg0, seg5);

  hipMemcpyAsync(seg3, v_first, (size_t)1048576*4, hipMemcpyDeviceToDevice, stream);
  hipMemcpyAsync(seg4, k_first, (size_t)1048576*4, hipMemcpyDeviceToDevice, stream);
}